// Round 7
// baseline (126.642 us; speedup 1.0000x reference)
//
#include <hip/hip_runtime.h>
#include <math.h>

#define BB 4
#define NN 512
#define DD 256
#define LL 64

#define WST 260   // 260 % 32 == 4: row stride 1040 B -> 8 consecutive rows'
                  // 16-B chunks tile the 128-B bank space exactly: b128 reads
                  // of 8-distinct-rows-x-8-lane-broadcast are conflict-free
#define IPB 4     // i-rows per k2 block: 512 blocks @ tiny LDS = 2 blocks/CU

// ---------------------------------------------------------------------------
// k1: xhat[b][n][l] = lw[l] * sum_d x[b][n][d] * W[l][d]
// LAYOUT CHANGE vs all prior rounds: output is [n][l] row-major (NOT [l][n]).
// This makes k2's per-thread read a contiguous 256-B row (16 b128) instead
// of a 64-instr stride-2KB column gather -- the root cause of round-1's
// spill and round-6's VMEM-latency bind.
// Compute mapping: l = (wave<<3)|(t&7), r = (t>>3)&7 -> each wave reads 8
// distinct W rows and 8 distinct x rows as 8-lane broadcasts (1-cycle bank
// service with WST=260), and the store hits 8 rows in 32-B contiguous runs.
// ---------------------------------------------------------------------------
__global__ __launch_bounds__(512) void k1_proj(const float* __restrict__ x,
                                               const float* __restrict__ Wp,
                                               const float* __restrict__ lw,
                                               float* __restrict__ xhat) {
  __shared__ __align__(16) float Wl[LL * WST];   // 66,560 B
  __shared__ __align__(16) float xs[8 * WST];    //  8,320 B
  const int bx   = blockIdx.x;
  const int b    = bx >> 6;             // NN/8 == 64 tiles per batch
  const int n0   = (bx & 63) * 8;
  const int t    = threadIdx.x;
  const int wave = t >> 6;
  const int lane = t & 63;

  // stage W: 4096 float4 / 512 threads = 8 iters; coalesced global reads,
  // b128 LDS writes (8 rows in flight per iter tile the bank space)
  const float4* Wp4 = (const float4*)Wp;
  #pragma unroll
  for (int it = 0; it < 8; ++it) {
    int idx = it * 512 + t;
    int ll  = idx >> 6;                 // W row (wave-uniform)
    int dq  = idx & 63;
    *(float4*)&Wl[ll * WST + dq * 4] = Wp4[idx];
  }
  // stage 8 x rows: one float4 per thread, coalesced
  {
    const float4* x4 = (const float4*)(x + ((size_t)b * NN + n0) * DD);
    *(float4*)&xs[wave * WST + lane * 4] = x4[t];
  }
  __syncthreads();

  const int l = (wave << 3) | (t & 7);  // 8 distinct W rows per wave
  const int r = (t >> 3) & 7;           // 8 distinct x rows per wave
  const float4* wrow = (const float4*)&Wl[l * WST];
  const float4* xrow = (const float4*)&xs[r * WST];
  float4 a = make_float4(0.f, 0.f, 0.f, 0.f);
  #pragma unroll 8
  for (int dd = 0; dd < 64; ++dd) {
    float4 wv = wrow[dd];
    float4 xv = xrow[dd];
    a.x += xv.x * wv.x;
    a.y += xv.y * wv.y;
    a.z += xv.z * wv.z;
    a.w += xv.w * wv.w;
  }
  // [n][l] store: lanes 0-7 write l..l+7 of row n0+r -> 32-B contiguous runs
  xhat[((size_t)b * NN + n0 + r) * LL + l] =
      lw[l] * ((a.x + a.y) + (a.z + a.w));  // lw>=0: w|a-b| == |wa-wb|
}

// ---------------------------------------------------------------------------
// k2: per (b, i-tile of IPB=4): dist -> leaky_relu -> rowmax -> adj*exp ->
//     rowsum -> divide -> +1e-10.  512 threads, thread = column j.
//
// With xhat in [n][l] layout, thread j's data is its OWN contiguous row:
// 16 x b128 VMEM loads (vs 64 stride-2KB dword gathers).  Each 4-l chunk is
// consumed immediately against the LDS xi tile (same-address b128 broadcast)
// -> max live xj state is a few chunks, no spill possible.
// VMEM instrs/thread: 16 xj + 4 adj + 1 xi-stage + 4 store  (was ~70+).
// LDS ~1.3 KB -> 512 blocks run 2/CU (16 waves) for latency hiding.
// ---------------------------------------------------------------------------
__global__ __launch_bounds__(512, 4) void k2_main(const float* __restrict__ xhat,
                                                  const float* __restrict__ adj,
                                                  float* __restrict__ out) {
  __shared__ __align__(16) float4 xi4[IPB * 16];  // [r][c]: IPB rows x 16 f4
  __shared__ float redm[IPB * 8];
  __shared__ float reds[IPB * 8];

  const int bx   = blockIdx.x;
  const int b    = bx >> 7;             // NN/IPB == 128 tiles per batch
  const int i0   = (bx & 127) * IPB;
  const int t    = threadIdx.x;         // j
  const int wave = t >> 6;
  const int lane = t & 63;

  const float* xbase = xhat + (size_t)b * NN * LL;

  // adj: the only HBM-cold read; issue all IPB upfront, hidden under l-loop
  const float* adjb = adj + ((size_t)b * NN + i0) * NN;
  float adjv[IPB];
  #pragma unroll
  for (int r = 0; r < IPB; ++r) adjv[r] = adjb[(size_t)r * NN + t];

  // stage xi tile: IPB contiguous 256-B rows -> 64 float4, threads 0-63
  if (t < IPB * 16)
    xi4[t] = ((const float4*)(xbase + (size_t)(i0 + (t >> 4)) * LL))[t & 15];
  __syncthreads();

  // dist: thread j streams its own contiguous xhat row in 16 b128 chunks
  const float4* xr = (const float4*)(xbase + (size_t)t * LL);
  float acc[IPB] = {0.f, 0.f, 0.f, 0.f};
  #pragma unroll
  for (int c = 0; c < 16; ++c) {
    float4 xj = xr[c];
    #pragma unroll
    for (int r = 0; r < IPB; ++r) {
      float4 xi = xi4[r * 16 + c];      // same-address broadcast b128
      acc[r] += fabsf(xi.x - xj.x) + fabsf(xi.y - xj.y) +
                fabsf(xi.z - xj.z) + fabsf(xi.w - xj.w);
    }
  }

  // leaky_relu (dist >= 0 in practice, but stay faithful)
  #pragma unroll
  for (int r = 0; r < IPB; ++r) {
    float d = acc[r];
    acc[r] = d >= 0.f ? d : 0.01f * d;
  }

  // row max over 512 j: wave shfl reduce, then cross-wave via LDS
  #pragma unroll
  for (int r = 0; r < IPB; ++r) {
    float m = acc[r];
    #pragma unroll
    for (int off = 32; off > 0; off >>= 1)
      m = fmaxf(m, __shfl_xor(m, off, 64));
    if (lane == 0) redm[r * 8 + wave] = m;
  }
  __syncthreads();

  float e[IPB];
  #pragma unroll
  for (int r = 0; r < IPB; ++r) {
    float m = redm[r * 8 + 0];
    #pragma unroll
    for (int k = 1; k < 8; ++k) m = fmaxf(m, redm[r * 8 + k]);
    e[r] = adjv[r] * __expf(acc[r] - m);
  }

  // row sum
  #pragma unroll
  for (int r = 0; r < IPB; ++r) {
    float s = e[r];
    #pragma unroll
    for (int off = 32; off > 0; off >>= 1)
      s += __shfl_xor(s, off, 64);
    if (lane == 0) reds[r * 8 + wave] = s;
  }
  __syncthreads();

  float* outb = out + ((size_t)b * NN + i0) * NN;
  #pragma unroll
  for (int r = 0; r < IPB; ++r) {
    float s = reds[r * 8 + 0];
    #pragma unroll
    for (int k = 1; k < 8; ++k) s += reds[r * 8 + k];
    outb[(size_t)r * NN + t] = e[r] / s + 1e-10f;     // epsilon AFTER division
  }
}

extern "C" void kernel_launch(void* const* d_in, const int* in_sizes, int n_in,
                              void* d_out, int out_size, void* d_ws, size_t ws_size,
                              hipStream_t stream) {
  const float* x   = (const float*)d_in[0];   // [B,N,D]
  const float* adj = (const float*)d_in[1];   // [B,N,N]
  const float* Wp  = (const float*)d_in[2];   // [L,D]
  const float* lw  = (const float*)d_in[3];   // [L]
  float* out  = (float*)d_out;                // [B,N,N]
  float* xhat = (float*)d_ws;                 // [B,N,L] = 512 KiB

  hipLaunchKernelGGL(k1_proj, dim3(BB * NN / 8), dim3(512), 0, stream,
                     x, Wp, lw, xhat);
  hipLaunchKernelGGL(k2_main, dim3(BB * NN / IPB), dim3(512), 0, stream,
                     xhat, adj, out);
}

// Round 8
// 86.120 us; speedup vs baseline: 1.4705x; 1.4705x over previous
//
#include <hip/hip_runtime.h>
#include <math.h>

#define BB 4
#define NN 512
#define DD 256
#define LL 64

#define WST 260  // 260 % 32 == 4: 8 consecutive rows' b128 chunks land on 8
                 // distinct 4-bank groups -> broadcast reads conflict-free
#define IPB 4    // i-rows per k2 block: 512 blocks @ tiny LDS = 2 blocks/CU

// ---------------------------------------------------------------------------
// k1: xhatT[b][l][n] = lw[l] * sum_d x[b][n][d] * W[l][d]      ([l][n] layout:
// j must be the fastest axis for k2's coalescing -- round-7's [n][l] was
// wave-scattered and spilled).
//
// ROUND-7 DIAGNOSIS: k1 ~20 us vs ~5 us LDS floor: both operands came from
// LDS -> 1024 dependent ds_read_b128 per CU on one pipe, 8 lockstep waves,
// latency-bound.  FIX: only W is staged in LDS; x is read straight from
// global.  The block's x-tile is 8 KB -> L1-resident after the first pass
// (each chunk re-read by all 8 waves), so the x stream rides the VMEM/L1
// pipe in parallel with W's LDS reads, and per-thread LDS reads halve
// (128 -> 64).  FMA chains unchanged (4 independent accumulators).
// ---------------------------------------------------------------------------
__global__ __launch_bounds__(512) void k1_proj(const float* __restrict__ x,
                                               const float* __restrict__ Wp,
                                               const float* __restrict__ lw,
                                               float* __restrict__ xhatT) {
  __shared__ __align__(16) float Wl[LL * WST];   // 66,560 B
  const int bx = blockIdx.x;
  const int b  = bx >> 6;               // NN/8 == 64 tiles per batch
  const int n0 = (bx & 63) * 8;
  const int t  = threadIdx.x;

  const int l = t >> 3;                 // wave w reads W rows 8w..8w+7
  const int r = t & 7;                  // 8 distinct x rows per wave

  float wl = lw[l];                     // issue early, consumed at the end

  // stage W: 4096 float4 / 512 threads = 8 iters; coalesced global reads,
  // conflict-free b128 LDS writes (8 rows in flight tile the bank space)
  const float4* Wp4 = (const float4*)Wp;
  #pragma unroll
  for (int it = 0; it < 8; ++it) {
    int idx = it * 512 + t;
    int ll  = idx >> 6;                 // W row (wave-uniform)
    int dq  = idx & 63;
    *(float4*)&Wl[ll * WST + dq * 4] = Wp4[idx];
  }
  __syncthreads();

  const float4* wrow = (const float4*)&Wl[l * WST];                 // LDS
  const float4* xrow = (const float4*)(x + ((size_t)b * NN + n0 + r) * DD);
  float4 a = make_float4(0.f, 0.f, 0.f, 0.f);
  #pragma unroll 8
  for (int dd = 0; dd < 64; ++dd) {
    float4 wv = wrow[dd];               // 8-lane broadcast, conflict-free
    float4 xv = xrow[dd];               // global: 8 distinct lines, L1-hot
    a.x += xv.x * wv.x;
    a.y += xv.y * wv.y;
    a.z += xv.z * wv.z;
    a.w += xv.w * wv.w;
  }
  // [l][n] store: lanes 0-7 (same l... lanes sharing l differ in r) ->
  // each 8-lane group writes 8 consecutive n's = 32-B runs
  xhatT[((size_t)b * LL + l) * NN + n0 + r] =
      wl * ((a.x + a.y) + (a.z + a.w));  // lw>=0: w|a-b| == |wa-wb|
}

// ---------------------------------------------------------------------------
// k2: VERBATIM round-6 version (measured ~13 us by subtraction).
// per (b, i-tile of IPB=4): dist -> leaky_relu -> rowmax -> adj*exp ->
// rowsum -> divide -> +1e-10.  512 threads, thread = column j.
//   - xj: xhatT[l][n] coalesced dword loads, L2-resident (512 KB);
//   - xi: block-uniform float4 loads (same address wave-wide -> merged);
//   - #pragma unroll 8 bounds load-hoist depth (full unroll = round-1 spill).
// LDS = 256 B -> 512 blocks run 2/CU (16 waves) for latency hiding.
// ---------------------------------------------------------------------------
__global__ __launch_bounds__(512, 4) void k2_main(const float* __restrict__ xhatT,
                                                  const float* __restrict__ adj,
                                                  float* __restrict__ out) {
  __shared__ float redm[IPB * 8];
  __shared__ float reds[IPB * 8];

  const int bx   = blockIdx.x;
  const int b    = bx >> 7;             // NN/IPB == 128 tiles per batch
  const int i0   = (bx & 127) * IPB;
  const int t    = threadIdx.x;         // j
  const int wave = t >> 6;
  const int lane = t & 63;

  const float* xb = xhatT + (size_t)b * (LL * NN);

  // adj: the only HBM-cold read; issue all IPB upfront, hidden under l-loop
  const float* adjb = adj + ((size_t)b * NN + i0) * NN;
  float adjv[IPB];
  #pragma unroll
  for (int r = 0; r < IPB; ++r) adjv[r] = adjb[(size_t)r * NN + t];

  float acc[IPB] = {0.f, 0.f, 0.f, 0.f};
  #pragma unroll 8
  for (int l = 0; l < LL; ++l) {
    float  p  = xb[l * NN + t];                       // coalesced, L2
    float4 xi = *(const float4*)(xb + l * NN + i0);   // uniform -> merged
    acc[0] += fabsf(xi.x - p);
    acc[1] += fabsf(xi.y - p);
    acc[2] += fabsf(xi.z - p);
    acc[3] += fabsf(xi.w - p);
  }

  // leaky_relu (dist >= 0 in practice, but stay faithful)
  #pragma unroll
  for (int r = 0; r < IPB; ++r) {
    float d = acc[r];
    acc[r] = d >= 0.f ? d : 0.01f * d;
  }

  // row max over 512 j: wave shfl reduce, then cross-wave via LDS
  #pragma unroll
  for (int r = 0; r < IPB; ++r) {
    float m = acc[r];
    #pragma unroll
    for (int off = 32; off > 0; off >>= 1)
      m = fmaxf(m, __shfl_xor(m, off, 64));
    if (lane == 0) redm[r * 8 + wave] = m;
  }
  __syncthreads();

  float e[IPB];
  #pragma unroll
  for (int r = 0; r < IPB; ++r) {
    float m = redm[r * 8 + 0];
    #pragma unroll
    for (int k = 1; k < 8; ++k) m = fmaxf(m, redm[r * 8 + k]);
    e[r] = adjv[r] * __expf(acc[r] - m);
  }

  // row sum
  #pragma unroll
  for (int r = 0; r < IPB; ++r) {
    float s = e[r];
    #pragma unroll
    for (int off = 32; off > 0; off >>= 1)
      s += __shfl_xor(s, off, 64);
    if (lane == 0) reds[r * 8 + wave] = s;
  }
  __syncthreads();

  float* outb = out + ((size_t)b * NN + i0) * NN;
  #pragma unroll
  for (int r = 0; r < IPB; ++r) {
    float s = reds[r * 8 + 0];
    #pragma unroll
    for (int k = 1; k < 8; ++k) s += reds[r * 8 + k];
    outb[(size_t)r * NN + t] = e[r] / s + 1e-10f;     // epsilon AFTER division
  }
}

extern "C" void kernel_launch(void* const* d_in, const int* in_sizes, int n_in,
                              void* d_out, int out_size, void* d_ws, size_t ws_size,
                              hipStream_t stream) {
  const float* x   = (const float*)d_in[0];   // [B,N,D]
  const float* adj = (const float*)d_in[1];   // [B,N,N]
  const float* Wp  = (const float*)d_in[2];   // [L,D]
  const float* lw  = (const float*)d_in[3];   // [L]
  float* out   = (float*)d_out;               // [B,N,N]
  float* xhatT = (float*)d_ws;                // [B,L,N] = 512 KiB

  hipLaunchKernelGGL(k1_proj, dim3(BB * NN / 8), dim3(512), 0, stream,
                     x, Wp, lw, xhatT);
  hipLaunchKernelGGL(k2_main, dim3(BB * NN / IPB), dim3(512), 0, stream,
                     xhatT, adj, out);
}

// Round 9
// 74.096 us; speedup vs baseline: 1.7092x; 1.1623x over previous
//
#include <hip/hip_runtime.h>
#include <math.h>

#define BB 4
#define NN 512
#define DD 256
#define LL 64

#define WST 260  // 260 % 32 == 4: 8 consecutive rows' b128 chunks land on 8
                 // distinct 16-B bank slots -> broadcast reads conflict-free
#define IPB 4    // i-rows per k2 block: 512 blocks @ tiny LDS = 2 blocks/CU

// ---------------------------------------------------------------------------
// k1: xhatT[b][l][n] = lw[l] * sum_d x[b][n][d] * W[l][d]   ([l][n] layout --
// j fastest for k2's coalescing; lw>=0 so w|a-b| == |wa-wb|).
//
// ROUND-9 CHANGE (granularity only; inner pattern byte-identical to round 6,
// the best measured config): split the l-dimension across 2 blocks.
//   block = 32 W-rows x 8 x-rows, 256 threads, one output/thread
//   LDS = 32*WST + 8*WST floats = 41.6 KB  -> 2 blocks resident/CU
//   grid = 4 b x 2 l-halves x 64 n-tiles = 512 = exactly 2 blocks/CU
// Same 8 waves/CU as round 6, but TWO independent barrier domains: one
// block's W/x staging overlaps the other's compute (round-6 had 1 block/CU,
// stage->vmcnt-drain->compute fully serialized).  Within-wave access
// pattern unchanged: l = t>>3 spans 8 rows/wave, r = t&7 spans 8 rows/wave,
// both b128 broadcast conflict-free at WST=260.
// ---------------------------------------------------------------------------
__global__ __launch_bounds__(256) void k1_proj(const float* __restrict__ x,
                                               const float* __restrict__ Wp,
                                               const float* __restrict__ lw,
                                               float* __restrict__ xhatT) {
  __shared__ __align__(16) float Wl[32 * WST];   // 33,280 B (W half)
  __shared__ __align__(16) float xs[8 * WST];    //  8,320 B
  const int bx = blockIdx.x;
  const int nt = bx & 63;               // n-tile (fastest: neighbors share W)
  const int lh = (bx >> 6) & 1;         // l-half
  const int b  = bx >> 7;
  const int n0 = nt * 8;
  const int t  = threadIdx.x;

  const int ll = t >> 3;                // 0..31: 8 distinct W rows per wave
  const int r  = t & 7;                 // 8 distinct x rows per wave

  float wl = lw[lh * 32 + ll];          // issue early, consumed at the end

  // stage W half: 2048 float4 / 256 threads = 8 iters; coalesced global,
  // conflict-free b128 LDS writes
  const float4* Wp4 = (const float4*)Wp + (size_t)lh * 32 * 64;
  #pragma unroll
  for (int it = 0; it < 8; ++it) {
    int idx = it * 256 + t;
    int lr  = idx >> 6;                 // 0..31 (wave-uniform)
    int dq  = idx & 63;
    *(float4*)&Wl[lr * WST + dq * 4] = Wp4[idx];
  }
  // stage 8 x rows: 512 float4 / 256 threads = 2 iters, coalesced
  {
    const float4* x4 = (const float4*)(x + ((size_t)b * NN + n0) * DD);
    #pragma unroll
    for (int it = 0; it < 2; ++it) {
      int idx = it * 256 + t;
      *(float4*)&xs[(idx >> 6) * WST + (idx & 63) * 4] = x4[idx];
    }
  }
  __syncthreads();

  const float4* wrow = (const float4*)&Wl[ll * WST];
  const float4* xrow = (const float4*)&xs[r * WST];
  float4 a = make_float4(0.f, 0.f, 0.f, 0.f);
  #pragma unroll 8
  for (int dd = 0; dd < 64; ++dd) {
    float4 wv = wrow[dd];               // 8 rows x 8-lane bcast, conflict-free
    float4 xv = xrow[dd];               // 8 rows x 8-lane bcast, conflict-free
    a.x += xv.x * wv.x;
    a.y += xv.y * wv.y;
    a.z += xv.z * wv.z;
    a.w += xv.w * wv.w;
  }
  // [l][n] store: each 8-lane group writes 8 consecutive n's = 32-B runs
  xhatT[((size_t)b * LL + lh * 32 + ll) * NN + n0 + r] =
      wl * ((a.x + a.y) + (a.z + a.w));
}

// ---------------------------------------------------------------------------
// k2: round-6 version (best measured, ~13 us by subtraction) with ONE tweak:
// #pragma unroll 8 -> 16, halving the vmcnt stall groups on the 64 serial
// L2-resident xj loads (16 dwords + 16 uniform-f4 in flight; far from the
// round-1 spill cliff which was the full-64 hoist).
// per (b, i-tile of IPB=4): dist -> leaky_relu -> rowmax -> adj*exp ->
// rowsum -> divide -> +1e-10.  512 threads, thread = column j.
// LDS = 256 B -> 512 blocks run 2/CU (16 waves) for latency hiding.
// ---------------------------------------------------------------------------
__global__ __launch_bounds__(512, 4) void k2_main(const float* __restrict__ xhatT,
                                                  const float* __restrict__ adj,
                                                  float* __restrict__ out) {
  __shared__ float redm[IPB * 8];
  __shared__ float reds[IPB * 8];

  const int bx   = blockIdx.x;
  const int b    = bx >> 7;             // NN/IPB == 128 tiles per batch
  const int i0   = (bx & 127) * IPB;
  const int t    = threadIdx.x;         // j
  const int wave = t >> 6;
  const int lane = t & 63;

  const float* xb = xhatT + (size_t)b * (LL * NN);

  // adj: the only HBM-cold read; issue all IPB upfront, hidden under l-loop
  const float* adjb = adj + ((size_t)b * NN + i0) * NN;
  float adjv[IPB];
  #pragma unroll
  for (int r = 0; r < IPB; ++r) adjv[r] = adjb[(size_t)r * NN + t];

  float acc[IPB] = {0.f, 0.f, 0.f, 0.f};
  #pragma unroll 16
  for (int l = 0; l < LL; ++l) {
    float  p  = xb[l * NN + t];                       // coalesced, L2
    float4 xi = *(const float4*)(xb + l * NN + i0);   // uniform -> s_load
    acc[0] += fabsf(xi.x - p);
    acc[1] += fabsf(xi.y - p);
    acc[2] += fabsf(xi.z - p);
    acc[3] += fabsf(xi.w - p);
  }

  // leaky_relu (dist >= 0 in practice, but stay faithful)
  #pragma unroll
  for (int r = 0; r < IPB; ++r) {
    float d = acc[r];
    acc[r] = d >= 0.f ? d : 0.01f * d;
  }

  // row max over 512 j: wave shfl reduce, then cross-wave via LDS
  #pragma unroll
  for (int r = 0; r < IPB; ++r) {
    float m = acc[r];
    #pragma unroll
    for (int off = 32; off > 0; off >>= 1)
      m = fmaxf(m, __shfl_xor(m, off, 64));
    if (lane == 0) redm[r * 8 + wave] = m;
  }
  __syncthreads();

  float e[IPB];
  #pragma unroll
  for (int r = 0; r < IPB; ++r) {
    float m = redm[r * 8 + 0];
    #pragma unroll
    for (int k = 1; k < 8; ++k) m = fmaxf(m, redm[r * 8 + k]);
    e[r] = adjv[r] * __expf(acc[r] - m);
  }

  // row sum
  #pragma unroll
  for (int r = 0; r < IPB; ++r) {
    float s = e[r];
    #pragma unroll
    for (int off = 32; off > 0; off >>= 1)
      s += __shfl_xor(s, off, 64);
    if (lane == 0) reds[r * 8 + wave] = s;
  }
  __syncthreads();

  float* outb = out + ((size_t)b * NN + i0) * NN;
  #pragma unroll
  for (int r = 0; r < IPB; ++r) {
    float s = reds[r * 8 + 0];
    #pragma unroll
    for (int k = 1; k < 8; ++k) s += reds[r * 8 + k];
    outb[(size_t)r * NN + t] = e[r] / s + 1e-10f;     // epsilon AFTER division
  }
}

extern "C" void kernel_launch(void* const* d_in, const int* in_sizes, int n_in,
                              void* d_out, int out_size, void* d_ws, size_t ws_size,
                              hipStream_t stream) {
  const float* x   = (const float*)d_in[0];   // [B,N,D]
  const float* adj = (const float*)d_in[1];   // [B,N,N]
  const float* Wp  = (const float*)d_in[2];   // [L,D]
  const float* lw  = (const float*)d_in[3];   // [L]
  float* out   = (float*)d_out;               // [B,N,N]
  float* xhatT = (float*)d_ws;                // [B,L,N] = 512 KiB

  hipLaunchKernelGGL(k1_proj, dim3(BB * 2 * (NN / 8)), dim3(256), 0, stream,
                     x, Wp, lw, xhatT);
  hipLaunchKernelGGL(k2_main, dim3(BB * NN / IPB), dim3(512), 0, stream,
                     xhatT, adj, out);
}